// Round 5
// baseline (906.240 us; speedup 1.0000x reference)
//
#include <hip/hip_runtime.h>
#include <stdint.h>
#include <math.h>

#define NR 65536
#define NC 256

__device__ __forceinline__ uint32_t f2key(float f) {
  uint32_t b = __float_as_uint(f);
  return (b & 0x80000000u) ? ~b : (b | 0x80000000u);
}

__global__ __launch_bounds__(256) void k_transpose_key(const float* __restrict__ in,
                                                       uint32_t* __restrict__ out) {
  __shared__ uint32_t tile[64][65];
  int tx = threadIdx.x & 63;
  int tw = threadIdx.x >> 6;
  int c0 = blockIdx.x * 64;
  int r0 = blockIdx.y * 64;
  for (int i = tw; i < 64; i += 4)
    tile[i][tx] = f2key(in[(size_t)(r0 + i) * NC + (c0 + tx)]);
  __syncthreads();
  for (int i = tw; i < 64; i += 4)
    out[(size_t)(c0 + i) * NR + (r0 + tx)] = tile[tx][i];
}

// Stable 8-bit counting-sort pass; one block per (array, column).
// CHUNK=8192 (8 keys/thread): digit runs avg 32 elems = full 128B lines.
__global__ __launch_bounds__(1024, 8) void k_radix_pass(
    const uint32_t* __restrict__ sX, uint32_t* __restrict__ dXb,
    const uint32_t* __restrict__ sH, uint32_t* __restrict__ dHb, int shift,
    const uint32_t* __restrict__ hInX, uint32_t* __restrict__ hOutX,
    const uint32_t* __restrict__ hInH, uint32_t* __restrict__ hOutH) {
  const int arr = blockIdx.x >> 8;
  const int col = blockIdx.x & 255;
  const uint32_t* src = (arr ? sH : sX) + (size_t)col * NR;
  uint32_t* dst = (arr ? dHb : dXb) + (size_t)col * NR;
  const uint32_t* histIn = arr ? hInH : hInX;
  uint32_t* histOut = arr ? hOutH : hOutX;

  __shared__ uint32_t waveCnt[16][256];
  __shared__ uint32_t waveOff[16][256];
  __shared__ uint32_t stage[8192];
  __shared__ uint32_t runoffP[2][256];
  __shared__ uint32_t chunkStart[256];
  __shared__ uint32_t nextHist[256];

  const int t = threadIdx.x;
  const int lane = t & 63, w = t >> 6;
  const uint64_t ltm = (1ULL << lane) - 1ULL;

  for (int i = t; i < 16 * 256; i += 1024) ((uint32_t*)waveCnt)[i] = 0;
  if (t < 256) nextHist[t] = 0;
  if (histIn) {
    if (t < 256) runoffP[0][t] = histIn[col * 256 + t];
  } else {
    if (t < 256) runoffP[0][t] = 0;
    __syncthreads();
    for (int i = t; i < NR; i += 1024)
      atomicAdd(&runoffP[0][(src[i] >> shift) & 255u], 1u);
  }
  __syncthreads();
  if (w == 0) {  // exclusive scan of digit hist into runoffP[0]; d = lane+64q
    uint32_t carry = 0;
#pragma unroll
    for (int q = 0; q < 4; ++q) {
      int d = lane + 64 * q;
      uint32_t v = runoffP[0][d];
      uint32_t inc = v;
      for (int off = 1; off < 64; off <<= 1) {
        uint32_t nn = __shfl_up(inc, off);
        if (lane >= off) inc += nn;
      }
      runoffP[0][d] = carry + inc - v;
      carry += __shfl(inc, 63);
    }
  }
  __syncthreads();

  int par = 0;
  uint32_t key[8];
#pragma unroll
  for (int k = 0; k < 8; ++k) key[k] = src[512 * w + 64 * k + lane];

  for (int cb = 0; cb < NR; cb += 8192) {
    uint32_t nxt[8];
    const bool more = (cb + 8192) < NR;
    if (more) {
#pragma unroll
      for (int k = 0; k < 8; ++k)
        nxt[k] = src[cb + 8192 + 512 * w + 64 * k + lane];
    }
    uint32_t rnk[8];
#pragma unroll
    for (int k = 0; k < 8; ++k) {  // wave-local stable ranking
      uint32_t d = (key[k] >> shift) & 255u;
      uint32_t pre = waveCnt[w][d];
      uint64_t m = ~0ULL;
#pragma unroll
      for (int b = 0; b < 8; ++b) {
        uint64_t bb = __ballot((d >> b) & 1u);
        m &= ((d >> b) & 1u) ? bb : ~bb;
      }
      uint32_t lower = (uint32_t)__popcll(m & ltm);
      rnk[k] = pre + lower;
      if (lower == 0) waveCnt[w][d] = pre + (uint32_t)__popcll(m);
      __builtin_amdgcn_wave_barrier();
    }
    __syncthreads();  // B1
    if (w == 0) {     // megaphase
      uint32_t carry = 0;
#pragma unroll
      for (int q = 0; q < 4; ++q) {
        int d = lane + 64 * q;
        uint32_t run = 0;
#pragma unroll
        for (int ww = 0; ww < 16; ++ww) {
          waveOff[ww][d] = run;
          run += waveCnt[ww][d];
          waveCnt[ww][d] = 0;
        }
        runoffP[par ^ 1][d] = runoffP[par][d] + run;
        uint32_t inc = run;
        for (int off = 1; off < 64; off <<= 1) {
          uint32_t nn = __shfl_up(inc, off);
          if (lane >= off) inc += nn;
        }
        chunkStart[d] = carry + inc - run;
        carry += __shfl(inc, 63);
      }
    }
    __syncthreads();  // B2
#pragma unroll
    for (int k = 0; k < 8; ++k) {
      uint32_t d = (key[k] >> shift) & 255u;
      stage[chunkStart[d] + waveOff[w][d] + rnk[k]] = key[k];
    }
    __syncthreads();  // B3
#pragma unroll
    for (int h = 0; h < 2; ++h) {
      uint4 sv = ((const uint4*)stage)[h * 1024 + t];  // ds_read_b128
      uint32_t se[4] = {sv.x, sv.y, sv.z, sv.w};
      int p0 = h * 4096 + 4 * t;
#pragma unroll
      for (int k = 0; k < 4; ++k) {
        uint32_t kk = se[k];
        uint32_t d = (kk >> shift) & 255u;
        dst[runoffP[par][d] + (uint32_t)(p0 + k) - chunkStart[d]] = kk;
        if (histOut) atomicAdd(&nextHist[(kk >> (shift + 8)) & 255u], 1u);
      }
    }
    par ^= 1;
    if (more) {
#pragma unroll
      for (int k = 0; k < 8; ++k) key[k] = nxt[k];
    }
  }
  if (histOut) {
    __syncthreads();
    if (t < 256) histOut[col * 256 + t] = nextHist[t];
  }
}

// Combined: ln table (blocks 0..256) + merge seeds (blocks 257..258)
__global__ __launch_bounds__(256) void k_prep(float2* __restrict__ tab,
                                              const uint32_t* __restrict__ xs,
                                              const uint32_t* __restrict__ xh,
                                              uint32_t* __restrict__ seed) {
  int bid = blockIdx.x, t = threadIdx.x;
  if (bid < 257) {
    int v = bid * 256 + t;
    if (v <= 65536) {
      float2 p;
      p.x = (float)log((double)(v + 1));
      p.y = (float)log((double)(65537 - v));
      tab[v] = p;
    }
  } else {
    int id = (bid - 257) * 256 + t;  // 0..511
    int col = id >> 1, half = id & 1;
    const uint32_t* A = xs + (size_t)col * NR;
    uint32_t v = xh[(size_t)col * NR + half * (NR / 2)];
    int lo = 0, hi = NR;
    while (lo < hi) {
      int mid = (lo + hi) >> 1;
      if (A[mid] <= v) lo = mid + 1; else hi = mid;
    }
    seed[id] = (uint32_t)lo;
  }
}

__global__ __launch_bounds__(1024, 8) void k_ad_accum(const uint32_t* __restrict__ xs,
                                                      const uint32_t* __restrict__ xh,
                                                      const uint32_t* __restrict__ seed,
                                                      const float2* __restrict__ tab,
                                                      double* __restrict__ colsum) {
  constexpr int BCH = 4096, CAPA = 6144;
  __shared__ uint32_t ldsB[BCH];
  __shared__ uint32_t ldsA[CAPA];
  __shared__ int sh_jnext;
  __shared__ double red[1024];
  const int bid = blockIdx.x, col = bid >> 1, half = bid & 1, t = threadIdx.x;
  const uint32_t* A = xs + (size_t)col * NR;
  const uint32_t* B = xh + (size_t)col * NR;
  int jb = (int)seed[bid];
  double acc = 0.0;
  const int base0 = half * (NR / 2);
  for (int r = 0; r < (NR / 2) / BCH; ++r) {
    int base = base0 + r * BCH;
#pragma unroll
    for (int k = 0; k < 4; ++k) ldsB[t + 1024 * k] = B[base + t + 1024 * k];
    int avail = min(CAPA, NR - jb);
    for (int i = t; i < avail; i += 1024) ldsA[i] = A[jb + i];
    __syncthreads();
    uint4 bv = ((const uint4*)ldsB)[t];
    uint32_t be[4] = {bv.x, bv.y, bv.z, bv.w};
    int lo = 0, hi = avail;
    while (lo < hi) {
      int mid = (lo + hi) >> 1;
      if (ldsA[mid] <= be[0]) lo = mid + 1; else hi = mid;
    }
    int j = lo;
    long jg = -1;
#pragma unroll
    for (int k = 0; k < 4; ++k) {
      uint32_t v = be[k];
      if (jg < 0) {
        while (j < avail && ldsA[j] <= v) ++j;
        if (j == avail && jb + avail < NR) jg = jb + avail;
      }
      if (jg >= 0) {
        while (jg < NR && A[jg] <= v) ++jg;
      }
      int cnt = (jg >= 0) ? (int)jg : jb + j;
      int i = base + 4 * t + k;
      float2 p = tab[cnt];
      acc += (double)((float)(2 * i + 1) * p.x + (float)(2 * NR - 1 - 2 * i) * p.y);
    }
    if (t == 1023) sh_jnext = (jg >= 0) ? (int)jg : jb + j;
    __syncthreads();
    jb = sh_jnext;
  }
  red[t] = acc;
  __syncthreads();
  for (int s = 512; s > 0; s >>= 1) {
    if (t < s) red[t] += red[t + s];
    __syncthreads();
  }
  if (t == 0) colsum[bid] = red[0];
}

__global__ __launch_bounds__(512) void k_final(const double* __restrict__ colsum,
                                               float* __restrict__ out) {
  __shared__ double red[512];
  int t = threadIdx.x;
  red[t] = colsum[t];
  __syncthreads();
  for (int s = 256; s > 0; s >>= 1) {
    if (t < s) red[t] += red[t + s];
    __syncthreads();
  }
  if (t == 0) {
    double total = red[0];
    double dist = -total / ((double)NR * (double)NC)
                  + 2.0 * (double)NR * log(65538.0) - (double)NR;
    out[0] = (float)dist;
  }
}

extern "C" void kernel_launch(void* const* d_in, const int* in_sizes, int n_in,
                              void* d_out, int out_size, void* d_ws, size_t ws_size,
                              hipStream_t stream) {
  const float* X = (const float*)d_in[0];
  const float* Xh = (const float*)d_in[1];
  float* out = (float*)d_out;

  const size_t NEL = (size_t)NC * NR;  // 64MB per buffer
  const size_t HIST = 256 * 256;
  uint32_t* P0 = (uint32_t*)d_ws;
  uint32_t* P1 = P0 + NEL;
  uint32_t* P2 = P1 + NEL;
  double* colsum = (double*)P1;        // carved from dead P1 after sorts
  uint32_t* seeds = P1 + 4096;
  float2* tab = (float2*)(P1 + 8192);

  dim3 tg(NC / 64, NR / 64);
  k_transpose_key<<<tg, 256, 0, stream>>>(X, P0);
  k_transpose_key<<<tg, 256, 0, stream>>>(Xh, P2);

  uint32_t* nul = nullptr;
  bool fused = ws_size >= (4 * NEL + 4 * HIST) * sizeof(uint32_t);
  if (fused) {
    uint32_t* P3 = P2 + NEL;
    uint32_t* h0X = P3 + NEL;
    uint32_t* h1X = h0X + HIST;
    uint32_t* h0H = h1X + HIST;
    uint32_t* h1H = h0H + HIST;
    k_radix_pass<<<512, 1024, 0, stream>>>(P0, P1, P2, P3, 0,  nul, h1X, nul, h1H);
    k_radix_pass<<<512, 1024, 0, stream>>>(P1, P0, P3, P2, 8,  h1X, h0X, h1H, h0H);
    k_radix_pass<<<512, 1024, 0, stream>>>(P0, P1, P2, P3, 16, h0X, h1X, h0H, h1H);
    k_radix_pass<<<512, 1024, 0, stream>>>(P1, P0, P3, P2, 24, h1X, nul, h1H, nul);
  } else {
    bool useHist = ws_size >= (3 * NEL + 2 * HIST) * sizeof(uint32_t);
    uint32_t* h0 = P2 + NEL;
    uint32_t* h1 = h0 + HIST;
#define HI(p) (useHist ? (p) : nul)
    k_radix_pass<<<256, 1024, 0, stream>>>(P0, P1, P0, P1, 0,  nul, HI(h1), nul, nul);
    k_radix_pass<<<256, 1024, 0, stream>>>(P1, P0, P1, P0, 8,  HI(h1), HI(h0), nul, nul);
    k_radix_pass<<<256, 1024, 0, stream>>>(P0, P1, P0, P1, 16, HI(h0), HI(h1), nul, nul);
    k_radix_pass<<<256, 1024, 0, stream>>>(P1, P0, P1, P0, 24, HI(h1), nul, nul, nul);
    k_radix_pass<<<256, 1024, 0, stream>>>(P2, P1, P2, P1, 0,  nul, HI(h1), nul, nul);
    k_radix_pass<<<256, 1024, 0, stream>>>(P1, P2, P1, P2, 8,  HI(h1), HI(h0), nul, nul);
    k_radix_pass<<<256, 1024, 0, stream>>>(P2, P1, P2, P1, 16, HI(h0), HI(h1), nul, nul);
    k_radix_pass<<<256, 1024, 0, stream>>>(P1, P2, P1, P2, 24, HI(h1), nul, nul, nul);
#undef HI
  }

  k_prep<<<259, 256, 0, stream>>>(tab, P0, P2, seeds);
  k_ad_accum<<<512, 1024, 0, stream>>>(P0, P2, seeds, tab, colsum);
  k_final<<<1, 512, 0, stream>>>(colsum, out);
}

// Round 6
// 900.413 us; speedup vs baseline: 1.0065x; 1.0065x over previous
//
#include <hip/hip_runtime.h>
#include <stdint.h>
#include <math.h>

#define NR 65536
#define NC 256

__device__ __forceinline__ uint32_t f2key(float f) {
  uint32_t b = __float_as_uint(f);
  return (b & 0x80000000u) ? ~b : (b | 0x80000000u);
}

// 64x64 tiled transpose [NR][NC] -> [NC][NR] for both arrays (z selects)
__global__ __launch_bounds__(256) void k_transpose_key(const float* __restrict__ X,
                                                       const float* __restrict__ Xh,
                                                       uint32_t* __restrict__ outX,
                                                       uint32_t* __restrict__ outH) {
  __shared__ uint32_t tile[64][65];
  const float* in = blockIdx.z ? Xh : X;
  uint32_t* out = blockIdx.z ? outH : outX;
  int tx = threadIdx.x & 63;
  int tw = threadIdx.x >> 6;
  int c0 = blockIdx.x * 64;
  int r0 = blockIdx.y * 64;
  for (int i = tw; i < 64; i += 4)
    tile[i][tx] = f2key(in[(size_t)(r0 + i) * NC + (c0 + tx)]);
  __syncthreads();
  for (int i = tw; i < 64; i += 4)
    out[(size_t)(c0 + i) * NR + (r0 + tx)] = tile[tx][i];
}

// Stable 8-bit counting-sort pass; one block per (array, column).
// CHUNK=8192, strided coalesced out-phase, 4-way split nextHist.
__global__ __launch_bounds__(1024, 8) void k_radix_pass(
    const uint32_t* __restrict__ sX, uint32_t* __restrict__ dXb,
    const uint32_t* __restrict__ sH, uint32_t* __restrict__ dHb, int shift,
    const uint32_t* __restrict__ hInX, uint32_t* __restrict__ hOutX,
    const uint32_t* __restrict__ hInH, uint32_t* __restrict__ hOutH) {
  const int arr = blockIdx.x >> 8;
  const int col = blockIdx.x & 255;
  const uint32_t* src = (arr ? sH : sX) + (size_t)col * NR;
  uint32_t* dst = (arr ? dHb : dXb) + (size_t)col * NR;
  const uint32_t* histIn = arr ? hInH : hInX;
  uint32_t* histOut = arr ? hOutH : hOutX;

  __shared__ uint32_t waveCnt[16][256];
  __shared__ uint32_t waveOff[16][256];
  __shared__ uint32_t stage[8192];
  __shared__ uint32_t runoffP[2][256];
  __shared__ uint32_t chunkStart[256];
  __shared__ uint32_t nextHist4[4][256];

  const int t = threadIdx.x;
  const int lane = t & 63, w = t >> 6;
  const uint64_t ltm = (1ULL << lane) - 1ULL;

  for (int i = t; i < 16 * 256; i += 1024) ((uint32_t*)waveCnt)[i] = 0;
  if (t < 4 * 256) ((uint32_t*)nextHist4)[t] = 0;
  if (histIn) {
    if (t < 256) runoffP[0][t] = histIn[col * 256 + t];
  } else {
    if (t < 256) runoffP[0][t] = 0;
    __syncthreads();
    // ballot-leader histogram: one atomic per (wave, distinct digit)
    for (int i = t; i < NR; i += 1024) {
      uint32_t d = (src[i] >> shift) & 255u;
      uint64_t m = ~0ULL;
#pragma unroll
      for (int b = 0; b < 8; ++b) {
        uint64_t bb = __ballot((d >> b) & 1u);
        m &= ((d >> b) & 1u) ? bb : ~bb;
      }
      if ((m & ltm) == 0) atomicAdd(&runoffP[0][d], (uint32_t)__popcll(m));
    }
  }
  __syncthreads();
  if (w == 0) {  // exclusive scan of digit hist into runoffP[0]; d = lane+64q
    uint32_t carry = 0;
#pragma unroll
    for (int q = 0; q < 4; ++q) {
      int d = lane + 64 * q;
      uint32_t v = runoffP[0][d];
      uint32_t inc = v;
      for (int off = 1; off < 64; off <<= 1) {
        uint32_t nn = __shfl_up(inc, off);
        if (lane >= off) inc += nn;
      }
      runoffP[0][d] = carry + inc - v;
      carry += __shfl(inc, 63);
    }
  }
  __syncthreads();

  int par = 0;
  uint32_t key[8];
#pragma unroll
  for (int k = 0; k < 8; ++k) key[k] = src[512 * w + 64 * k + lane];

  for (int cb = 0; cb < NR; cb += 8192) {
    uint32_t nxt[8];
    const bool more = (cb + 8192) < NR;
    if (more) {
#pragma unroll
      for (int k = 0; k < 8; ++k)
        nxt[k] = src[cb + 8192 + 512 * w + 64 * k + lane];
    }
    uint32_t rnk[8];
#pragma unroll
    for (int k = 0; k < 8; ++k) {  // wave-local stable ranking
      uint32_t d = (key[k] >> shift) & 255u;
      uint32_t pre = waveCnt[w][d];
      uint64_t m = ~0ULL;
#pragma unroll
      for (int b = 0; b < 8; ++b) {
        uint64_t bb = __ballot((d >> b) & 1u);
        m &= ((d >> b) & 1u) ? bb : ~bb;
      }
      uint32_t lower = (uint32_t)__popcll(m & ltm);
      rnk[k] = pre + lower;
      if (lower == 0) waveCnt[w][d] = pre + (uint32_t)__popcll(m);
      __builtin_amdgcn_wave_barrier();
    }
    __syncthreads();  // B1
    if (w == 0) {     // megaphase
      uint32_t carry = 0;
#pragma unroll
      for (int q = 0; q < 4; ++q) {
        int d = lane + 64 * q;
        uint32_t run = 0;
#pragma unroll
        for (int ww = 0; ww < 16; ++ww) {
          waveOff[ww][d] = run;
          run += waveCnt[ww][d];
          waveCnt[ww][d] = 0;
        }
        runoffP[par ^ 1][d] = runoffP[par][d] + run;
        uint32_t inc = run;
        for (int off = 1; off < 64; off <<= 1) {
          uint32_t nn = __shfl_up(inc, off);
          if (lane >= off) inc += nn;
        }
        chunkStart[d] = carry + inc - run;
        carry += __shfl(inc, 63);
      }
    }
    __syncthreads();  // B2
#pragma unroll
    for (int k = 0; k < 8; ++k) {
      uint32_t d = (key[k] >> shift) & 255u;
      stage[chunkStart[d] + waveOff[w][d] + rnk[k]] = key[k];
    }
    __syncthreads();  // B3
#pragma unroll
    for (int k = 0; k < 8; ++k) {
      int p = t + 1024 * k;               // consecutive lanes -> consecutive dst
      uint32_t kk = stage[p];
      uint32_t d = (kk >> shift) & 255u;
      dst[runoffP[par][d] + (uint32_t)p - chunkStart[d]] = kk;
      if (histOut) atomicAdd(&nextHist4[w >> 2][(kk >> (shift + 8)) & 255u], 1u);
    }
    par ^= 1;
    if (more) {
#pragma unroll
      for (int k = 0; k < 8; ++k) key[k] = nxt[k];
    }
  }
  if (histOut) {
    __syncthreads();
    if (t < 256)
      histOut[col * 256 + t] =
          nextHist4[0][t] + nextHist4[1][t] + nextHist4[2][t] + nextHist4[3][t];
  }
}

// Combined: ln table (blocks 0..256) + merge seeds (blocks 257..260, 1024 seeds)
__global__ __launch_bounds__(256) void k_prep(float2* __restrict__ tab,
                                              const uint32_t* __restrict__ xs,
                                              const uint32_t* __restrict__ xh,
                                              uint32_t* __restrict__ seed) {
  int bid = blockIdx.x, t = threadIdx.x;
  if (bid < 257) {
    int v = bid * 256 + t;
    if (v <= 65536) {
      float2 p;
      p.x = (float)log((double)(v + 1));
      p.y = (float)log((double)(65537 - v));
      tab[v] = p;
    }
  } else {
    int id = (bid - 257) * 256 + t;  // 0..1023
    int col = id >> 2, q = id & 3;
    const uint32_t* A = xs + (size_t)col * NR;
    uint32_t v = xh[(size_t)col * NR + q * (NR / 4)];
    int lo = 0, hi = NR;
    while (lo < hi) {
      int mid = (lo + hi) >> 1;
      if (A[mid] <= v) lo = mid + 1; else hi = mid;
    }
    seed[id] = (uint32_t)lo;
  }
}

// LDS-staged merge + AD accumulation via ln-table gathers; quarter-columns.
__global__ __launch_bounds__(1024, 8) void k_ad_accum(const uint32_t* __restrict__ xs,
                                                      const uint32_t* __restrict__ xh,
                                                      const uint32_t* __restrict__ seed,
                                                      const float2* __restrict__ tab,
                                                      double* __restrict__ colsum) {
  constexpr int BCH = 4096, CAPA = 6144;
  __shared__ uint32_t ldsB[BCH];
  __shared__ uint32_t ldsA[CAPA];
  __shared__ int sh_jnext;
  __shared__ double red16[16];
  const int bid = blockIdx.x, col = bid >> 2, q = bid & 3, t = threadIdx.x;
  const int lane = t & 63, w = t >> 6;
  const uint32_t* A = xs + (size_t)col * NR;
  const uint32_t* B = xh + (size_t)col * NR;
  int jb = (int)seed[bid];
  double acc = 0.0;
  const int base0 = q * (NR / 4);
  for (int r = 0; r < (NR / 4) / BCH; ++r) {
    int base = base0 + r * BCH;
#pragma unroll
    for (int k = 0; k < 4; ++k) ldsB[t + 1024 * k] = B[base + t + 1024 * k];
    int avail = min(CAPA, NR - jb);
    for (int i = t; i < avail; i += 1024) ldsA[i] = A[jb + i];
    __syncthreads();
    uint4 bv = ((const uint4*)ldsB)[t];
    uint32_t be[4] = {bv.x, bv.y, bv.z, bv.w};
    int lo = 0, hi = avail;
    while (lo < hi) {
      int mid = (lo + hi) >> 1;
      if (ldsA[mid] <= be[0]) lo = mid + 1; else hi = mid;
    }
    int j = lo;
    long jg = -1;  // rare window-overflow fallback (global walk)
#pragma unroll
    for (int k = 0; k < 4; ++k) {
      uint32_t v = be[k];
      if (jg < 0) {
        while (j < avail && ldsA[j] <= v) ++j;
        if (j == avail && jb + avail < NR) jg = jb + avail;
      }
      if (jg >= 0) {
        while (jg < NR && A[jg] <= v) ++jg;
      }
      int cnt = (jg >= 0) ? (int)jg : jb + j;
      int i = base + 4 * t + k;
      float2 p = tab[cnt];  // {ln(cnt+1), ln(65537-cnt)}
      acc += (double)((float)(2 * i + 1) * p.x + (float)(2 * NR - 1 - 2 * i) * p.y);
    }
    if (t == 1023) sh_jnext = (jg >= 0) ? (int)jg : jb + j;
    __syncthreads();
    jb = sh_jnext;
  }
  // wave shuffle-reduce then 16-slot LDS reduce
  for (int off = 32; off > 0; off >>= 1) acc += __shfl_down(acc, off);
  if (lane == 0) red16[w] = acc;
  __syncthreads();
  if (t == 0) {
    double s = 0.0;
#pragma unroll
    for (int i = 0; i < 16; ++i) s += red16[i];
    colsum[bid] = s;
  }
}

__global__ __launch_bounds__(1024) void k_final(const double* __restrict__ colsum,
                                                float* __restrict__ out) {
  __shared__ double red16[16];
  int t = threadIdx.x, lane = t & 63, w = t >> 6;
  double v = colsum[t];
  for (int off = 32; off > 0; off >>= 1) v += __shfl_down(v, off);
  if (lane == 0) red16[w] = v;
  __syncthreads();
  if (t == 0) {
    double total = 0.0;
#pragma unroll
    for (int i = 0; i < 16; ++i) total += red16[i];
    double dist = -total / ((double)NR * (double)NC)
                  + 2.0 * (double)NR * log(65538.0) - (double)NR;
    out[0] = (float)dist;
  }
}

extern "C" void kernel_launch(void* const* d_in, const int* in_sizes, int n_in,
                              void* d_out, int out_size, void* d_ws, size_t ws_size,
                              hipStream_t stream) {
  const float* X = (const float*)d_in[0];
  const float* Xh = (const float*)d_in[1];
  float* out = (float*)d_out;

  const size_t NEL = (size_t)NC * NR;  // 64MB per buffer
  const size_t HIST = 256 * 256;
  uint32_t* P0 = (uint32_t*)d_ws;
  uint32_t* P1 = P0 + NEL;
  uint32_t* P2 = P1 + NEL;
  // carved from dead P1 after sorts: colsum 8KB @0, seeds 4KB @16KB, tab 524KB @32KB
  double* colsum = (double*)P1;
  uint32_t* seeds = P1 + 4096;
  float2* tab = (float2*)(P1 + 8192);

  dim3 tg(NC / 64, NR / 64, 2);
  k_transpose_key<<<tg, 256, 0, stream>>>(X, Xh, P0, P2);

  uint32_t* nul = nullptr;
  bool fused = ws_size >= (4 * NEL + 4 * HIST) * sizeof(uint32_t);
  if (fused) {
    uint32_t* P3 = P2 + NEL;
    uint32_t* h0X = P3 + NEL;
    uint32_t* h1X = h0X + HIST;
    uint32_t* h0H = h1X + HIST;
    uint32_t* h1H = h0H + HIST;
    k_radix_pass<<<512, 1024, 0, stream>>>(P0, P1, P2, P3, 0,  nul, h1X, nul, h1H);
    k_radix_pass<<<512, 1024, 0, stream>>>(P1, P0, P3, P2, 8,  h1X, h0X, h1H, h0H);
    k_radix_pass<<<512, 1024, 0, stream>>>(P0, P1, P2, P3, 16, h0X, h1X, h0H, h1H);
    k_radix_pass<<<512, 1024, 0, stream>>>(P1, P0, P3, P2, 24, h1X, nul, h1H, nul);
  } else {
    bool useHist = ws_size >= (3 * NEL + 2 * HIST) * sizeof(uint32_t);
    uint32_t* h0 = P2 + NEL;
    uint32_t* h1 = h0 + HIST;
#define HI(p) (useHist ? (p) : nul)
    k_radix_pass<<<256, 1024, 0, stream>>>(P0, P1, P0, P1, 0,  nul, HI(h1), nul, nul);
    k_radix_pass<<<256, 1024, 0, stream>>>(P1, P0, P1, P0, 8,  HI(h1), HI(h0), nul, nul);
    k_radix_pass<<<256, 1024, 0, stream>>>(P0, P1, P0, P1, 16, HI(h0), HI(h1), nul, nul);
    k_radix_pass<<<256, 1024, 0, stream>>>(P1, P0, P1, P0, 24, HI(h1), nul, nul, nul);
    k_radix_pass<<<256, 1024, 0, stream>>>(P2, P1, P2, P1, 0,  nul, HI(h1), nul, nul);
    k_radix_pass<<<256, 1024, 0, stream>>>(P1, P2, P1, P2, 8,  HI(h1), HI(h0), nul, nul);
    k_radix_pass<<<256, 1024, 0, stream>>>(P2, P1, P2, P1, 16, HI(h0), HI(h1), nul, nul);
    k_radix_pass<<<256, 1024, 0, stream>>>(P1, P2, P1, P2, 24, HI(h1), nul, nul, nul);
#undef HI
  }

  k_prep<<<261, 256, 0, stream>>>(tab, P0, P2, seeds);
  k_ad_accum<<<1024, 1024, 0, stream>>>(P0, P2, seeds, tab, colsum);
  k_final<<<1, 1024, 0, stream>>>(colsum, out);
}